// Round 19
// baseline (357.534 us; speedup 1.0000x reference)
//
#include <hip/hip_runtime.h>
#include <math.h>

#define HW 65536
#define DD 160
#define NB 2
#define DCH 40
#define NSL (DCH + 6)   // 46 marched slices per chunk incl. halo
#define NCH 4
#define TW 16
#define TH 8
#define PH 15           // h-pitch in f32x2 units (14 rows + 1 pad)

#define SSIM_C1 1e-4f
#define SSIM_C2 9e-4f

typedef float f32x2 __attribute__((ext_vector_type(2)));

struct Gw { float g[7]; };

static __device__ __forceinline__ f32x2 s2(float v) { f32x2 r; r.x = v; r.y = v; return r; }

// Fused SSIM3D v19: 4 AUTONOMOUS waves per 256-thread workgroup, zero in-march
// barriers. Each wave owns a 16w x 8h tile (block covers 64w x 8h) with R18's
// machinery: depth-2 ping-pong register prefetch, u/v 4-field algebra,
// double-buffered per-wave LDS planes (disjoint slots by wid -> no hazards).
// R18 proved correctness + no-spill but hit a 1-wave-workgroup slot cap
// (~7 waves/CU); packing 4 waves/workgroup lifts residency to ~20 waves/CU.
__global__ __launch_bounds__(256, 1) void k_fused(
    const float* __restrict__ img1, const float* __restrict__ img2,
    Gw gw, float* __restrict__ partials)
{
    __shared__ f32x2 pUV[4][2][TW][PH];   // [wave][buf][w][h]
    __shared__ f32x2 pSQ[4][2][TW][PH];
    __shared__ float red[4];

    const int tid = threadIdx.x;
    const int wid = tid >> 6;          // wave 0..3
    const int lane = tid & 63;
    const int nb = blockIdx.z >> 2;
    const int o0 = (blockIdx.z & 3) * DCH;
    const int h0 = blockIdx.y * TH;
    const int w0 = blockIdx.x * 64 + wid * TW;   // wave's 16-wide strip
    const float* i1 = img1 + (size_t)nb * DD * HW;
    const float* i2 = img2 + (size_t)nb * DD * HW;

    // ---- W geometry: lanes 0..55: row hh = lane>>2 (0..13), quad wb ----
    const bool wth = (lane < 56);
    const int hh = lane >> 2;
    const int wb = (lane & 3) * 4;
    const int gh = h0 - 3 + hh;
    const int gwb = w0 - 3 + wb;
    const bool ghv = wth && ((unsigned)gh < 256u);
    const int ghc = gh < 0 ? 0 : (gh > 255 ? 255 : gh);
    int coff[10];
    float mx[10];
#pragma unroll
    for (int i = 0; i < 10; ++i) {
        int gwi = gwb + i;
        int gc = gwi < 0 ? 0 : (gwi > 255 ? 255 : gwi);
        coff[i] = ghc * 256 + gc;                  // always-in-bounds address
        mx[i] = (ghv && gwi == gc) ? 1.f : 0.f;    // zero-pad multiplier
    }

    // ---- H/D geometry: all 64 lanes, 2 output rows each ----
    const int wcol = lane & 15;
    const int hb = (lane >> 4) * 2;   // 0,2,4,6

    f32x2 ringUV[2][7] = {};
    f32x2 ringSQ[2][7] = {};
    float lsum = 0.f;
    f32x2 cA[10], cB[10];   // depth-2 ping-pong slice buffers (raw x,y)

    // raw slice loader: 20 independent loads, NO dependent VALU at issue site
    auto LOADTO = [&](f32x2 (&buf)[10], int s) {
        const float* p1 = i1 + (size_t)s * HW;
        const float* p2 = i2 + (size_t)s * HW;
#pragma unroll
        for (int i = 0; i < 10; ++i) buf[i].x = p1[coff[i]];
#pragma unroll
        for (int i = 0; i < 10; ++i) buf[i].y = p2[coff[i]];
    };

    // prologue: slice r=0 -> cA, r=1 -> cB (skipped if out of range; W for
    // those r is also skipped, so buffer contents don't matter)
    {
        const int s0 = o0 - 3;
        if (s0 >= 0 && wth) LOADTO(cA, s0);
        const int s1 = o0 - 2;
        if (s1 >= 0 && wth) LOADTO(cB, s1);
    }

#define PHASE(Q, CUR)                                                         \
    {                                                                         \
        const int r = 14 * t2 + (Q);                                          \
        if (r <= NSL) {                                                       \
            const int scur = o0 - 3 + r;                                      \
            /* 1) W-pass consumes CUR (loaded 2 phases ago) -> planes */      \
            if (wth && (r < NSL) && (scur >= 0) && (scur < DD)) {             \
                f32x2 aUV[4] = {};                                            \
                f32x2 aSQ[4] = {};                                            \
                _Pragma("unroll")                                             \
                for (int i = 0; i < 10; ++i) {                                \
                    f32x2 uv;                                                 \
                    uv.x = CUR[i].x + CUR[i].y;                               \
                    uv.y = CUR[i].x - CUR[i].y;                               \
                    uv = uv * s2(mx[i]);                                      \
                    const f32x2 sq = uv * uv;                                 \
                    _Pragma("unroll")                                         \
                    for (int o = 0; o < 4; ++o) {                             \
                        const int k = i - o;                                  \
                        if (k >= 0 && k < 7) {                                \
                            const float gk = gw.g[k];                         \
                            aUV[o] += s2(gk) * uv;                            \
                            aSQ[o] += s2(gk) * sq;                            \
                        }                                                     \
                    }                                                         \
                }                                                             \
                _Pragma("unroll")                                             \
                for (int o = 0; o < 4; ++o) {                                 \
                    pUV[wid][(Q) & 1][wb + o][hh] = aUV[o];                   \
                    pSQ[wid][(Q) & 1][wb + o][hh] = aSQ[o];                   \
                }                                                             \
            }                                                                 \
            /* 2) depth-2 prefetch: slice r+2 into CUR (consumed at r+2) */   \
            {                                                                 \
                const int sn2 = scur + 2;                                     \
                if (wth && (r + 2 < NSL) && (sn2 >= 0) && (sn2 < DD))         \
                    LOADTO(CUR, sn2);                                         \
            }                                                                 \
            /* 3) H-pass + D-ring + SSIM for rp = r-1 (other plane buffer; */ \
            /*    written LAST phase by THIS wave -> in-order DS pipe) */     \
            if (r >= 1) {                                                     \
                const int rp = r - 1;                                         \
                const int sp = o0 - 3 + rp;                                   \
                if (sp >= 0 && sp < DD) {                                     \
                    f32x2 vU[8], vS[8];                                       \
                    _Pragma("unroll")                                         \
                    for (int i = 0; i < 8; ++i) {                             \
                        vU[i] = pUV[wid][((Q) + 1) & 1][wcol][hb + i];        \
                        vS[i] = pSQ[wid][((Q) + 1) & 1][wcol][hb + i];        \
                    }                                                         \
                    _Pragma("unroll")                                         \
                    for (int o = 0; o < 2; ++o) {                             \
                        f32x2 aU = s2(0.f), aS = s2(0.f);                     \
                        _Pragma("unroll")                                     \
                        for (int k = 0; k < 7; ++k) {                         \
                            const float gk = gw.g[k];                         \
                            aU += s2(gk) * vU[o + k];                         \
                            aS += s2(gk) * vS[o + k];                         \
                        }                                                     \
                        ringUV[o][((Q) + 6) % 7] = aU;                        \
                        ringSQ[o][((Q) + 6) % 7] = aS;                        \
                    }                                                         \
                } else {                                                      \
                    _Pragma("unroll")                                         \
                    for (int o = 0; o < 2; ++o) {                             \
                        ringUV[o][((Q) + 6) % 7] = s2(0.f);                   \
                        ringSQ[o][((Q) + 6) % 7] = s2(0.f);                   \
                    }                                                         \
                }                                                             \
                if (r >= 7) {                                                 \
                    _Pragma("unroll")                                         \
                    for (int o = 0; o < 2; ++o) {                             \
                        f32x2 cU = s2(0.f), cS = s2(0.f);                     \
                        _Pragma("unroll")                                     \
                        for (int k = 0; k < 7; ++k) {                         \
                            const float gk = gw.g[k];                         \
                            const int pp = (((Q) + 6) % 7 + 1 + k) % 7;       \
                            cU += s2(gk) * ringUV[o][pp];                     \
                            cS += s2(gk) * ringSQ[o][pp];                     \
                        }                                                     \
                        /* A=conv(u), B=conv(v), P=conv(u^2), Q=conv(v^2) */  \
                        const f32x2 ab2 = cU * cU;                            \
                        const float sAB = ab2.x + ab2.y;                      \
                        const float dAB = ab2.x - ab2.y;                      \
                        const float sPQ = cS.x + cS.y;                        \
                        const float dPQ = cS.x - cS.y;                        \
                        const float num1 = 0.5f * dAB + SSIM_C1;              \
                        const float num2 = 0.5f * (dPQ - dAB) + SSIM_C2;      \
                        const float den1 = 0.5f * sAB + SSIM_C1;              \
                        const float den2 = 0.5f * (sPQ - sAB) + SSIM_C2;      \
                        lsum += (num1 * num2) *                               \
                                __builtin_amdgcn_rcpf(den1 * den2);           \
                    }                                                         \
                }                                                             \
            }                                                                 \
        }                                                                     \
    }

    for (int t2 = 0; t2 < 4; ++t2) {
        PHASE(0, cA)  PHASE(1, cB)  PHASE(2, cA)  PHASE(3, cB)
        PHASE(4, cA)  PHASE(5, cB)  PHASE(6, cA)  PHASE(7, cB)
        PHASE(8, cA)  PHASE(9, cB)  PHASE(10, cA) PHASE(11, cB)
        PHASE(12, cA) PHASE(13, cB)
    }
#undef PHASE

    // per-wave shuffle reduce, then one cross-wave reduction (only barrier)
#pragma unroll
    for (int off = 32; off > 0; off >>= 1)
        lsum += __shfl_down(lsum, off, 64);
    if (lane == 0) red[wid] = lsum;
    __syncthreads();
    if (tid == 0)
        partials[(blockIdx.z * gridDim.y + blockIdx.y) * gridDim.x + blockIdx.x] =
            red[0] + red[1] + red[2] + red[3];
}

__global__ __launch_bounds__(256) void k_final(
    const float* __restrict__ partials, int n, float scale, float* __restrict__ out)
{
    __shared__ float red[256];
    float s = 0.f;
    for (int i = threadIdx.x; i < n; i += 256) s += partials[i];
    red[threadIdx.x] = s;
    __syncthreads();
    for (int off = 128; off > 0; off >>= 1) {
        if (threadIdx.x < off) red[threadIdx.x] += red[threadIdx.x + off];
        __syncthreads();
    }
    if (threadIdx.x == 0) out[0] = red[0] * scale;
}

extern "C" void kernel_launch(void* const* d_in, const int* in_sizes, int n_in,
                              void* d_out, int out_size, void* d_ws, size_t ws_size,
                              hipStream_t stream)
{
    const float* img1 = (const float*)d_in[0];
    const float* img2 = (const float*)d_in[1];
    float* out = (float*)d_out;
    float* partials = (float*)d_ws;

    Gw gw;
    {
        double gs[7], sum = 0.0;
        for (int i = 0; i < 7; ++i) { double x = i - 3; gs[i] = exp(-x * x / 4.5); sum += gs[i]; }
        for (int i = 0; i < 7; ++i) gw.g[i] = (float)(gs[i] / sum);
    }

    dim3 grid(4, 32, NB * NCH);   // 4 x 32 x 8 = 1024 blocks, 4 waves each
    k_fused<<<grid, dim3(256), 0, stream>>>(img1, img2, gw, partials);
    k_final<<<dim3(1), dim3(256), 0, stream>>>(
        partials, 4 * 32 * NB * NCH, (float)(1.0 / 20971520.0), out);
}

// Round 20
// 201.192 us; speedup vs baseline: 1.7771x; 1.7771x over previous
//
#include <hip/hip_runtime.h>
#include <math.h>

#define HW 65536
#define DD 160
#define NB 2
#define DCH 40
#define NSL (DCH + 6)   // 46 marched slices per chunk incl. halo
#define NCH 4
#define TW 32
#define TH 8
#define PH 15           // h-pitch (14 rows + 1 pad, odd)

#define SSIM_C1 1e-4f
#define SSIM_C2 9e-4f

typedef float f32x2 __attribute__((ext_vector_type(2)));

struct Gw { float g[7]; };

static __device__ __forceinline__ f32x2 s2(float v) { f32x2 r; r.x = v; r.y = v; return r; }

// Fused SSIM3D v20: 128-thread (2-wave) blocks, 2048 blocks (8/CU).
// Machinery = champion R15: depth-2 ping-pong register prefetch (cA/cB),
// u/v 4-field algebra in two packed f32x2 planes, double-buffered transposed
// LDS planes, ONE __syncthreads per slice, 14-phase compile-time unroll.
// Rationale: barrier-synced cooperative blocks beat autonomous waves (R15 vs
// R18/19) at equal busy; smaller barrier groups + more independent blocks/CU
// interleave stall phases better. W-pass lane utilization 69% -> 87.5%.
__global__ __launch_bounds__(128, 1) void k_fused(
    const float* __restrict__ img1, const float* __restrict__ img2,
    Gw gw, float* __restrict__ partials)
{
    __shared__ f32x2 pUV[2][TW][PH];   // (conv_w u, conv_w v)
    __shared__ f32x2 pSQ[2][TW][PH];   // (conv_w u^2, conv_w v^2)
    __shared__ float red[128];

    const int tid = threadIdx.x;
    const int nb = blockIdx.z >> 2;
    const int o0 = (blockIdx.z & 3) * DCH;
    const int h0 = blockIdx.y * TH;
    const int w0 = blockIdx.x * TW;
    const float* i1 = img1 + (size_t)nb * DD * HW;
    const float* i2 = img2 + (size_t)nb * DD * HW;

    // ---- W geometry (tid < 112): row hh (0..13), 4 outputs at wb ----
    const bool wth = (tid < 112);
    const int hh = tid >> 3;
    const int wb = (tid & 7) * 4;
    const int gh = h0 - 3 + hh;
    const int gwb = w0 - 3 + wb;
    const bool ghv = wth && ((unsigned)gh < 256u);
    const int ghc = gh < 0 ? 0 : (gh > 255 ? 255 : gh);
    int coff[10];
    float mx[10];
#pragma unroll
    for (int i = 0; i < 10; ++i) {
        int gwi = gwb + i;
        int gc = gwi < 0 ? 0 : (gwi > 255 ? 255 : gwi);
        coff[i] = ghc * 256 + gc;                  // always-in-bounds address
        mx[i] = (ghv && gwi == gc) ? 1.f : 0.f;    // zero-pad multiplier
    }

    // ---- H/D geometry: all 128 threads, 2 output rows each ----
    const int wcol = tid & 31;
    const int hb = (tid >> 5) * 2;   // 0,2,4,6

    f32x2 ringUV[2][7] = {};
    f32x2 ringSQ[2][7] = {};
    float lsum = 0.f;
    f32x2 cA[10], cB[10];   // depth-2 ping-pong slice buffers (raw x,y)

    // raw slice loader: 20 independent loads, NO dependent VALU at issue site
    auto LOADTO = [&](f32x2 (&buf)[10], int s) {
        const float* p1 = i1 + (size_t)s * HW;
        const float* p2 = i2 + (size_t)s * HW;
#pragma unroll
        for (int i = 0; i < 10; ++i) buf[i].x = p1[coff[i]];
#pragma unroll
        for (int i = 0; i < 10; ++i) buf[i].y = p2[coff[i]];
    };

    // prologue: slice r=0 -> cA, r=1 -> cB (skipped if out of range; W for
    // those r is also skipped, so buffer contents don't matter)
    {
        const int s0 = o0 - 3;
        if (s0 >= 0 && wth) LOADTO(cA, s0);
        const int s1 = o0 - 2;
        if (s1 >= 0 && wth) LOADTO(cB, s1);
    }

#define PHASE(Q, CUR)                                                         \
    {                                                                         \
        const int r = 14 * t2 + (Q);                                          \
        if (r <= NSL) {                                                       \
            const int scur = o0 - 3 + r;                                      \
            /* 1) W-pass consumes CUR (loaded 2 phases ago) -> planes */      \
            if (wth && (r < NSL) && (scur >= 0) && (scur < DD)) {             \
                f32x2 aUV[4] = {};                                            \
                f32x2 aSQ[4] = {};                                            \
                _Pragma("unroll")                                             \
                for (int i = 0; i < 10; ++i) {                                \
                    f32x2 uv;                                                 \
                    uv.x = CUR[i].x + CUR[i].y;                               \
                    uv.y = CUR[i].x - CUR[i].y;                               \
                    uv = uv * s2(mx[i]);                                      \
                    const f32x2 sq = uv * uv;                                 \
                    _Pragma("unroll")                                         \
                    for (int o = 0; o < 4; ++o) {                             \
                        const int k = i - o;                                  \
                        if (k >= 0 && k < 7) {                                \
                            const float gk = gw.g[k];                         \
                            aUV[o] += s2(gk) * uv;                            \
                            aSQ[o] += s2(gk) * sq;                            \
                        }                                                     \
                    }                                                         \
                }                                                             \
                _Pragma("unroll")                                             \
                for (int o = 0; o < 4; ++o) {                                 \
                    pUV[(Q) & 1][wb + o][hh] = aUV[o];                        \
                    pSQ[(Q) & 1][wb + o][hh] = aSQ[o];                        \
                }                                                             \
            }                                                                 \
            /* 2) depth-2 prefetch: slice r+2 into CUR (consumed at r+2) */   \
            {                                                                 \
                const int sn2 = scur + 2;                                     \
                if (wth && (r + 2 < NSL) && (sn2 >= 0) && (sn2 < DD))         \
                    LOADTO(CUR, sn2);                                         \
            }                                                                 \
            /* 3) H-pass + D-ring + SSIM for rp = r-1 (other plane buffer) */ \
            if (r >= 1) {                                                     \
                const int rp = r - 1;                                         \
                const int sp = o0 - 3 + rp;                                   \
                if (sp >= 0 && sp < DD) {                                     \
                    f32x2 vU[8], vS[8];                                       \
                    _Pragma("unroll")                                         \
                    for (int i = 0; i < 8; ++i) {                             \
                        vU[i] = pUV[((Q) + 1) & 1][wcol][hb + i];             \
                        vS[i] = pSQ[((Q) + 1) & 1][wcol][hb + i];             \
                    }                                                         \
                    _Pragma("unroll")                                         \
                    for (int o = 0; o < 2; ++o) {                             \
                        f32x2 aU = s2(0.f), aS = s2(0.f);                     \
                        _Pragma("unroll")                                     \
                        for (int k = 0; k < 7; ++k) {                         \
                            const float gk = gw.g[k];                         \
                            aU += s2(gk) * vU[o + k];                         \
                            aS += s2(gk) * vS[o + k];                         \
                        }                                                     \
                        ringUV[o][((Q) + 6) % 7] = aU;                        \
                        ringSQ[o][((Q) + 6) % 7] = aS;                        \
                    }                                                         \
                } else {                                                      \
                    _Pragma("unroll")                                         \
                    for (int o = 0; o < 2; ++o) {                             \
                        ringUV[o][((Q) + 6) % 7] = s2(0.f);                   \
                        ringSQ[o][((Q) + 6) % 7] = s2(0.f);                   \
                    }                                                         \
                }                                                             \
                if (r >= 7) {                                                 \
                    _Pragma("unroll")                                         \
                    for (int o = 0; o < 2; ++o) {                             \
                        f32x2 cU = s2(0.f), cS = s2(0.f);                     \
                        _Pragma("unroll")                                     \
                        for (int k = 0; k < 7; ++k) {                         \
                            const float gk = gw.g[k];                         \
                            const int pp = (((Q) + 6) % 7 + 1 + k) % 7;       \
                            cU += s2(gk) * ringUV[o][pp];                     \
                            cS += s2(gk) * ringSQ[o][pp];                     \
                        }                                                     \
                        /* A=conv(u), B=conv(v), P=conv(u^2), Q=conv(v^2) */  \
                        const f32x2 ab2 = cU * cU;                            \
                        const float sAB = ab2.x + ab2.y;                      \
                        const float dAB = ab2.x - ab2.y;                      \
                        const float sPQ = cS.x + cS.y;                        \
                        const float dPQ = cS.x - cS.y;                        \
                        const float num1 = 0.5f * dAB + SSIM_C1;              \
                        const float num2 = 0.5f * (dPQ - dAB) + SSIM_C2;      \
                        const float den1 = 0.5f * sAB + SSIM_C1;              \
                        const float den2 = 0.5f * (sPQ - sAB) + SSIM_C2;      \
                        lsum += (num1 * num2) *                               \
                                __builtin_amdgcn_rcpf(den1 * den2);           \
                    }                                                         \
                }                                                             \
            }                                                                 \
            __syncthreads();                                                  \
        }                                                                     \
    }

    for (int t2 = 0; t2 < 4; ++t2) {
        PHASE(0, cA)  PHASE(1, cB)  PHASE(2, cA)  PHASE(3, cB)
        PHASE(4, cA)  PHASE(5, cB)  PHASE(6, cA)  PHASE(7, cB)
        PHASE(8, cA)  PHASE(9, cB)  PHASE(10, cA) PHASE(11, cB)
        PHASE(12, cA) PHASE(13, cB)
    }
#undef PHASE

    // deterministic block reduction
    red[tid] = lsum;
    __syncthreads();
    for (int off = 64; off > 0; off >>= 1) {
        if (tid < off) red[tid] += red[tid + off];
        __syncthreads();
    }
    if (tid == 0)
        partials[(blockIdx.z * gridDim.y + blockIdx.y) * gridDim.x + blockIdx.x] = red[0];
}

__global__ __launch_bounds__(256) void k_final(
    const float* __restrict__ partials, int n, float scale, float* __restrict__ out)
{
    __shared__ float red[256];
    float s = 0.f;
    for (int i = threadIdx.x; i < n; i += 256) s += partials[i];
    red[threadIdx.x] = s;
    __syncthreads();
    for (int off = 128; off > 0; off >>= 1) {
        if (threadIdx.x < off) red[threadIdx.x] += red[threadIdx.x + off];
        __syncthreads();
    }
    if (threadIdx.x == 0) out[0] = red[0] * scale;
}

extern "C" void kernel_launch(void* const* d_in, const int* in_sizes, int n_in,
                              void* d_out, int out_size, void* d_ws, size_t ws_size,
                              hipStream_t stream)
{
    const float* img1 = (const float*)d_in[0];
    const float* img2 = (const float*)d_in[1];
    float* out = (float*)d_out;
    float* partials = (float*)d_ws;

    Gw gw;
    {
        double gs[7], sum = 0.0;
        for (int i = 0; i < 7; ++i) { double x = i - 3; gs[i] = exp(-x * x / 4.5); sum += gs[i]; }
        for (int i = 0; i < 7; ++i) gw.g[i] = (float)(gs[i] / sum);
    }

    dim3 grid(256 / TW, 256 / TH, NB * NCH);   // 8 x 32 x 8 = 2048 blocks (8/CU)
    k_fused<<<grid, dim3(128), 0, stream>>>(img1, img2, gw, partials);
    k_final<<<dim3(1), dim3(256), 0, stream>>>(
        partials, (256 / TW) * (256 / TH) * NB * NCH, (float)(1.0 / 20971520.0), out);
}

// Round 21
// 151.578 us; speedup vs baseline: 2.3588x; 1.3273x over previous
//
#include <hip/hip_runtime.h>
#include <math.h>

#define HW 65536
#define DD 160
#define NB 2
#define DCH 40
#define NSL (DCH + 6)   // 46 marched slices per chunk incl. halo
#define NCH 4
#define TW 32
#define TH 16
#define PH 23           // h-pitch (odd -> 2-way LDS access, free)

#define SSIM_C1 1e-4f
#define SSIM_C2 9e-4f

typedef float f32x2 __attribute__((ext_vector_type(2)));

struct Gw { float g[7]; };

static __device__ __forceinline__ f32x2 s2(float v) { f32x2 r; r.x = v; r.y = v; return r; }

// Fused SSIM3D v21 == v15 (champion, resubmitted): depth-2 ping-pong register
// prefetch (slice r consumes buf[r&1] loaded at r-2, refills with r+2;
// 14-phase compile-time unroll; raw-load issue sites; multiplier masking at
// consumption) + u/v field algebra (u=x+y, v=x-y -> 4 conv fields
// {u,v,u^2,v^2} in two f32x2 planes). 256-thread blocks, 1024 blocks,
// double-buffered transposed LDS planes, ONE __syncthreads per slice.
// Best measured: 152 us total. The ~100us latency/barrier floor survived
// attacks on block size, barrier density, pipeline depth, autonomy, and
// algebra (R7-R20); this is the plateau configuration.
__global__ __launch_bounds__(256, 2) void k_fused(
    const float* __restrict__ img1, const float* __restrict__ img2,
    Gw gw, float* __restrict__ partials)
{
    __shared__ f32x2 pUV[2][TW][PH];   // (conv_w u, conv_w v)
    __shared__ f32x2 pSQ[2][TW][PH];   // (conv_w u^2, conv_w v^2)
    __shared__ float red[256];

    const int tid = threadIdx.x;
    const int nb = blockIdx.z >> 2;
    const int o0 = (blockIdx.z & 3) * DCH;
    const int h0 = blockIdx.y * TH;
    const int w0 = blockIdx.x * TW;
    const float* i1 = img1 + (size_t)nb * DD * HW;
    const float* i2 = img2 + (size_t)nb * DD * HW;

    // ---- W-thread geometry (tid < 176): row hh (0..21), 4 outputs at wb ----
    const bool wth = (tid < 176);
    const int hh = tid >> 3;
    const int wb = (tid & 7) * 4;
    const int gh = h0 - 3 + hh;
    const int gwb = w0 - 3 + wb;
    const bool ghv = wth && ((unsigned)gh < 256u);
    const int ghc = gh < 0 ? 0 : (gh > 255 ? 255 : gh);
    int coff[10];
    float mx[10];
#pragma unroll
    for (int i = 0; i < 10; ++i) {
        int gwi = gwb + i;
        int gc = gwi < 0 ? 0 : (gwi > 255 ? 255 : gwi);
        coff[i] = ghc * 256 + gc;                      // always-in-bounds address
        mx[i] = (ghv && gwi == gc) ? 1.f : 0.f;        // zero-pad multiplier
    }

    // ---- H/D geometry: all 256 threads, 2 output rows each ----
    const int wcol = tid & 31;
    const int hb = (tid >> 5) * 2;   // 0..14

    f32x2 ringUV[2][7] = {};
    f32x2 ringSQ[2][7] = {};
    float lsum = 0.f;
    f32x2 cA[10], cB[10];   // depth-2 ping-pong slice buffers (raw x,y)

    // raw slice loader: 20 independent loads, NO dependent VALU at issue site
    auto LOADTO = [&](f32x2 (&buf)[10], int s) {
        const float* p1 = i1 + (size_t)s * HW;
        const float* p2 = i2 + (size_t)s * HW;
#pragma unroll
        for (int i = 0; i < 10; ++i) buf[i].x = p1[coff[i]];
#pragma unroll
        for (int i = 0; i < 10; ++i) buf[i].y = p2[coff[i]];
    };

    // prologue: slice r=0 -> cA, slice r=1 -> cB (skipped if out of range;
    // W-pass is also skipped for those r, so buffer contents don't matter)
    {
        const int s0 = o0 - 3;
        if (s0 >= 0 && wth) LOADTO(cA, s0);
        const int s1 = o0 - 2;
        if (s1 >= 0 && wth) LOADTO(cB, s1);
    }

#define PHASE(Q, CUR)                                                         \
    {                                                                         \
        const int r = 14 * t2 + (Q);                                          \
        if (r <= NSL) {                                                       \
            const int scur = o0 - 3 + r;                                      \
            const bool wv = (r < NSL) && (scur >= 0) && (scur < DD);          \
            /* 1) W-pass consumes CUR (loaded 2 iterations ago) */            \
            if (wv && wth) {                                                  \
                f32x2 aUV[4] = {};                                            \
                f32x2 aSQ[4] = {};                                            \
                _Pragma("unroll")                                             \
                for (int i = 0; i < 10; ++i) {                                \
                    f32x2 uv;                                                 \
                    uv.x = CUR[i].x + CUR[i].y;                               \
                    uv.y = CUR[i].x - CUR[i].y;                               \
                    uv = uv * s2(mx[i]);                                      \
                    const f32x2 sq = uv * uv;                                 \
                    _Pragma("unroll")                                         \
                    for (int o = 0; o < 4; ++o) {                             \
                        const int k = i - o;                                  \
                        if (k >= 0 && k < 7) {                                \
                            const float gk = gw.g[k];                         \
                            aUV[o] += s2(gk) * uv;                            \
                            aSQ[o] += s2(gk) * sq;                            \
                        }                                                     \
                    }                                                         \
                }                                                             \
                _Pragma("unroll")                                             \
                for (int o = 0; o < 4; ++o) {                                 \
                    pUV[(Q) & 1][wb + o][hh] = aUV[o];                        \
                    pSQ[(Q) & 1][wb + o][hh] = aSQ[o];                        \
                }                                                             \
            }                                                                 \
            /* 2) depth-2 prefetch: slice r+2 into CUR (consumed at r+2) */   \
            {                                                                 \
                const int sn2 = scur + 2;                                     \
                if ((r + 2 < NSL) && (sn2 >= 0) && (sn2 < DD) && wth)         \
                    LOADTO(CUR, sn2);                                         \
            }                                                                 \
            /* 3) H-pass + D-ring + SSIM for rp = r-1 (other plane buffer) */ \
            if (r >= 1) {                                                     \
                const int rp = r - 1;                                         \
                const int sp = o0 - 3 + rp;                                   \
                if (sp >= 0 && sp < DD) {                                     \
                    f32x2 vU[8], vS[8];                                       \
                    _Pragma("unroll")                                         \
                    for (int i = 0; i < 8; ++i) {                             \
                        vU[i] = pUV[((Q) + 1) & 1][wcol][hb + i];             \
                        vS[i] = pSQ[((Q) + 1) & 1][wcol][hb + i];             \
                    }                                                         \
                    _Pragma("unroll")                                         \
                    for (int o = 0; o < 2; ++o) {                             \
                        f32x2 aU = s2(0.f), aS = s2(0.f);                     \
                        _Pragma("unroll")                                     \
                        for (int k = 0; k < 7; ++k) {                         \
                            const float gk = gw.g[k];                         \
                            aU += s2(gk) * vU[o + k];                         \
                            aS += s2(gk) * vS[o + k];                         \
                        }                                                     \
                        ringUV[o][((Q) + 6) % 7] = aU;                        \
                        ringSQ[o][((Q) + 6) % 7] = aS;                        \
                    }                                                         \
                } else {                                                      \
                    _Pragma("unroll")                                         \
                    for (int o = 0; o < 2; ++o) {                             \
                        ringUV[o][((Q) + 6) % 7] = s2(0.f);                   \
                        ringSQ[o][((Q) + 6) % 7] = s2(0.f);                   \
                    }                                                         \
                }                                                             \
                if (r >= 7) {                                                 \
                    _Pragma("unroll")                                         \
                    for (int o = 0; o < 2; ++o) {                             \
                        f32x2 cU = s2(0.f), cS = s2(0.f);                     \
                        _Pragma("unroll")                                     \
                        for (int k = 0; k < 7; ++k) {                         \
                            const float gk = gw.g[k];                         \
                            const int pp = (((Q) + 6) % 7 + 1 + k) % 7;       \
                            cU += s2(gk) * ringUV[o][pp];                     \
                            cS += s2(gk) * ringSQ[o][pp];                     \
                        }                                                     \
                        /* A=conv(u), B=conv(v), P=conv(u^2), Q=conv(v^2) */  \
                        const f32x2 ab2 = cU * cU;                            \
                        const float sAB = ab2.x + ab2.y;                      \
                        const float dAB = ab2.x - ab2.y;                      \
                        const float sPQ = cS.x + cS.y;                        \
                        const float dPQ = cS.x - cS.y;                        \
                        const float num1 = 0.5f * dAB + SSIM_C1;              \
                        const float num2 = 0.5f * (dPQ - dAB) + SSIM_C2;      \
                        const float den1 = 0.5f * sAB + SSIM_C1;              \
                        const float den2 = 0.5f * (sPQ - sAB) + SSIM_C2;      \
                        lsum += (num1 * num2) *                               \
                                __builtin_amdgcn_rcpf(den1 * den2);           \
                    }                                                         \
                }                                                             \
            }                                                                 \
            __syncthreads();                                                  \
        }                                                                     \
    }

    for (int t2 = 0; t2 < 4; ++t2) {
        PHASE(0, cA)  PHASE(1, cB)  PHASE(2, cA)  PHASE(3, cB)
        PHASE(4, cA)  PHASE(5, cB)  PHASE(6, cA)  PHASE(7, cB)
        PHASE(8, cA)  PHASE(9, cB)  PHASE(10, cA) PHASE(11, cB)
        PHASE(12, cA) PHASE(13, cB)
    }
#undef PHASE

    // deterministic block reduction
    red[tid] = lsum;
    __syncthreads();
    for (int off = 128; off > 0; off >>= 1) {
        if (tid < off) red[tid] += red[tid + off];
        __syncthreads();
    }
    if (tid == 0)
        partials[(blockIdx.z * gridDim.y + blockIdx.y) * gridDim.x + blockIdx.x] = red[0];
}

__global__ __launch_bounds__(256) void k_final(
    const float* __restrict__ partials, int n, float scale, float* __restrict__ out)
{
    __shared__ float red[256];
    float s = 0.f;
    for (int i = threadIdx.x; i < n; i += 256) s += partials[i];
    red[threadIdx.x] = s;
    __syncthreads();
    for (int off = 128; off > 0; off >>= 1) {
        if (threadIdx.x < off) red[threadIdx.x] += red[threadIdx.x + off];
        __syncthreads();
    }
    if (threadIdx.x == 0) out[0] = red[0] * scale;
}

extern "C" void kernel_launch(void* const* d_in, const int* in_sizes, int n_in,
                              void* d_out, int out_size, void* d_ws, size_t ws_size,
                              hipStream_t stream)
{
    const float* img1 = (const float*)d_in[0];
    const float* img2 = (const float*)d_in[1];
    float* out = (float*)d_out;
    float* partials = (float*)d_ws;

    Gw gw;
    {
        double gs[7], sum = 0.0;
        for (int i = 0; i < 7; ++i) { double x = i - 3; gs[i] = exp(-x * x / 4.5); sum += gs[i]; }
        for (int i = 0; i < 7; ++i) gw.g[i] = (float)(gs[i] / sum);
    }

    dim3 grid(256 / TW, 256 / TH, NB * NCH);   // 8 x 16 x 8 = 1024 blocks
    k_fused<<<grid, dim3(256), 0, stream>>>(img1, img2, gw, partials);
    k_final<<<dim3(1), dim3(256), 0, stream>>>(
        partials, (256 / TW) * (256 / TH) * NB * NCH, (float)(1.0 / 20971520.0), out);
}